// Round 10
// baseline (243.951 us; speedup 1.0000x reference)
//
#include <hip/hip_runtime.h>
#include <hip/hip_bf16.h>
#include <math.h>

#define D      256
#define N2     8192
#define NHALF  4096
#define TILE   128
#define BK     64
#define NCH    4        // 256 / BK
#define LDW    68       // LDS row stride in bf16 (136 B): bank start = 2*row+4*quad -> exact 2-way (free, r5-verified 0 conflicts)
#define NBLK2  4096     // sim grid: 64x64 tiles, one per block (r5-verified)

typedef __bf16 bf16x8_t __attribute__((ext_vector_type(8)));
typedef __bf16 bf16x4_t __attribute__((ext_vector_type(4)));
typedef float  f32x4_t  __attribute__((ext_vector_type(4)));

// ---------------- kernel 1: fused normalize + positives + denom/ticket zero --------
__global__ __launch_bounds__(256) void prep_kernel(const float* __restrict__ a,
                                                   const float* __restrict__ b,
                                                   __bf16* __restrict__ zb,
                                                   float* __restrict__ g_pos,
                                                   float* __restrict__ g_denom,
                                                   unsigned* __restrict__ g_ticket) {
    const int tid = threadIdx.x;
    const int gt  = blockIdx.x * 256 + tid;
    if (gt < N2) g_denom[gt] = 0.0f;
    if (gt == 0) *g_ticket = 0u;

    const int w = blockIdx.x * 4 + (tid >> 6);  // pair row in [0, NHALF)
    const int l = tid & 63;
    float4 x = ((const float4*)(a + (size_t)w * D))[l];
    float4 y = ((const float4*)(b + (size_t)w * D))[l];
    float sxx = x.x * x.x + x.y * x.y + x.z * x.z + x.w * x.w;
    float syy = y.x * y.x + y.y * y.y + y.z * y.z + y.w * y.w;
    float sxy = x.x * y.x + x.y * y.y + x.z * y.z + x.w * y.w;
    #pragma unroll
    for (int off = 32; off; off >>= 1) {
        sxx += __shfl_xor(sxx, off, 64);
        syy += __shfl_xor(syy, off, 64);
        sxy += __shfl_xor(sxy, off, 64);
    }
    const float rx = 1.0f / fmaxf(sqrtf(sxx), 1e-8f);
    const float ry = 1.0f / fmaxf(sqrtf(syy), 1e-8f);

    bf16x4_t ox, oy;
    ox[0] = (__bf16)(x.x * rx); ox[1] = (__bf16)(x.y * rx);
    ox[2] = (__bf16)(x.z * rx); ox[3] = (__bf16)(x.w * rx);
    oy[0] = (__bf16)(y.x * ry); oy[1] = (__bf16)(y.y * ry);
    oy[2] = (__bf16)(y.z * ry); oy[3] = (__bf16)(y.w * ry);
    *(bf16x4_t*)(zb + (size_t)w * D + l * 4)           = ox;
    *(bf16x4_t*)(zb + (size_t)(w + NHALF) * D + l * 4) = oy;

    if (l == 0) {
        const float p = sxy * rx * ry;
        g_pos[w]         = p;
        g_pos[w + NHALF] = p;
    }
}

// ---------------- kernel 2: round-5 sim (byte-exact) + last-block ticket fin -------
// Composition of the ONLY two individually-verified wins: (a) round-5 reg-staged LDS
// sim -- 66us, VGPR 88, 0 bank conflicts (LDW=68: bank start = 2*row+4*quad = exact
// 2-way, free per m136); (b) last-block ticket fin -- correctness-verified rounds
// 7/8/9, saves ~13-18us of launch overhead vs a separate fin kernel.
// Round-9 lesson: LDW=36 put all reads on even banks 4-way (4.2M conflicts, 1.58x);
// round-8: global_load_lds at K=256 is all pipeline-fill (no steady state); round-7:
// (256,4) caps VGPR at 128 and spills the 64-reg acc. This round changes NOTHING
// inside the sim loop relative to round 5.
__global__ __launch_bounds__(256, 2) void sim_kernel(const __bf16* __restrict__ zb,
                                                     float* __restrict__ g_denom,
                                                     const float* __restrict__ g_pos,
                                                     unsigned* __restrict__ g_ticket,
                                                     float* __restrict__ out) {
    __shared__ __bf16 ldsA[2][TILE * LDW];
    __shared__ __bf16 ldsB[2][TILE * LDW];
    __shared__ float  sw[4];
    __shared__ bool   amLast;

    const int tid    = threadIdx.x;
    const int l      = tid & 63;
    const int lane15 = l & 15;
    const int quad   = l >> 4;
    const int w      = tid >> 6;
    const int wr     = (w >> 1) * 64;          // wave row offset in tile
    const int wc     = (w & 1) * 64;           // wave col offset in tile

    const int bi = blockIdx.x >> 6;            // row block [0,64)
    const int bj = blockIdx.x & 63;            // col block [0,64)

    // staging map: thread t -> row r = t>>1, half = t&1 (64 B each), 4 x b128 units
    const int r    = tid >> 1;
    const int half = tid & 1;
    const __bf16* ga = zb + (size_t)(bi * TILE + r) * D + half * 32;
    const __bf16* gb = zb + (size_t)(bj * TILE + r) * D + half * 32;
    const int wofs = r * LDW + half * 32;

    bf16x8_t sa[4], sb[4];
    auto load_regs = [&](int c) {
        const int k0 = c * BK;
        #pragma unroll
        for (int u = 0; u < 4; ++u) {
            sa[u] = *(const bf16x8_t*)(ga + k0 + u * 8);
            sb[u] = *(const bf16x8_t*)(gb + k0 + u * 8);
        }
    };
    auto write_lds = [&](int buf) {
        #pragma unroll
        for (int u = 0; u < 4; ++u) {
            *(bf16x8_t*)(&ldsA[buf][wofs + u * 8]) = sa[u];
            *(bf16x8_t*)(&ldsB[buf][wofs + u * 8]) = sb[u];
        }
    };

    f32x4_t acc[4][4];
    #pragma unroll
    for (int mi = 0; mi < 4; ++mi)
        #pragma unroll
        for (int nj = 0; nj < 4; ++nj)
            acc[mi][nj] = (f32x4_t){0.f, 0.f, 0.f, 0.f};

    auto compute = [&](int buf) {
        #pragma unroll
        for (int ks = 0; ks < 2; ++ks) {
            bf16x8_t af[4], bff[4];
            #pragma unroll
            for (int mi = 0; mi < 4; ++mi)
                af[mi] = *(const bf16x8_t*)(&ldsA[buf][(wr + mi * 16 + lane15) * LDW + ks * 32 + quad * 8]);
            #pragma unroll
            for (int nj = 0; nj < 4; ++nj)
                bff[nj] = *(const bf16x8_t*)(&ldsB[buf][(wc + nj * 16 + lane15) * LDW + ks * 32 + quad * 8]);
            #pragma unroll
            for (int mi = 0; mi < 4; ++mi)
                #pragma unroll
                for (int nj = 0; nj < 4; ++nj)
                    acc[mi][nj] = __builtin_amdgcn_mfma_f32_16x16x32_bf16(bff[nj], af[mi], acc[mi][nj], 0, 0, 0);
        }
    };

    // prologue: stage chunk 0
    load_regs(0);
    write_lds(0);
    __syncthreads();

    int cur = 0;
    #pragma unroll
    for (int c = 0; c < NCH; ++c) {
        if (c + 1 < NCH) load_regs(c + 1);
        compute(cur);
        if (c + 1 < NCH) {
            write_lds(cur ^ 1);     // safe: buf[cur^1] readers all passed prior barrier
            __syncthreads();
            cur ^= 1;
        }
    }

    // epilogue: e = exp(sim/T) = exp2(acc * 2/ln2); zero self-similarity; row sums
    // acc[mi][nj]: S-row = bi*128+wr+mi*16+lane15, S-col = bj*128+wc+nj*16+quad*4+t
    const bool dw = (bi == bj) && (wr == wc);
    float rs[4] = {0.f, 0.f, 0.f, 0.f};
    #pragma unroll
    for (int mi = 0; mi < 4; ++mi) {
        #pragma unroll
        for (int nj = 0; nj < 4; ++nj) {
            #pragma unroll
            for (int t = 0; t < 4; ++t) {
                float e = exp2f(acc[mi][nj][t] * 2.8853900817779268f);
                if (dw && mi == nj && (quad * 4 + t) == lane15) e = 0.0f;
                rs[mi] += e;
            }
        }
    }
    // reduce the 4 quads holding the same row, then one atomic per row
    #pragma unroll
    for (int mi = 0; mi < 4; ++mi) {
        rs[mi] += __shfl_xor(rs[mi], 16, 64);
        rs[mi] += __shfl_xor(rs[mi], 32, 64);
    }
    if (l < 16) {
        #pragma unroll
        for (int mi = 0; mi < 4; ++mi)
            atomicAdd(&g_denom[bi * TILE + wr + mi * 16 + l], rs[mi]);
    }

    // ---------------- last-block fin (verified rounds 7-9) ----------------
    if (tid == 0) {
        __threadfence();
        unsigned t = __hip_atomic_fetch_add(g_ticket, 1u, __ATOMIC_ACQ_REL,
                                            __HIP_MEMORY_SCOPE_AGENT);
        amLast = (t == NBLK2 - 1);
    }
    __syncthreads();
    if (!amLast) return;

    float local = 0.0f;
    for (int k = tid; k < N2; k += 256) {
        float dn = __hip_atomic_load(&g_denom[k], __ATOMIC_RELAXED,
                                     __HIP_MEMORY_SCOPE_AGENT);
        local += logf(dn) - 2.0f * g_pos[k];
    }
    #pragma unroll
    for (int off = 32; off; off >>= 1) local += __shfl_xor(local, off, 64);
    if (l == 0) sw[tid >> 6] = local;
    __syncthreads();
    if (tid == 0) out[0] = (sw[0] + sw[1] + sw[2] + sw[3]) / (float)N2;
}

extern "C" void kernel_launch(void* const* d_in, const int* in_sizes, int n_in,
                              void* d_out, int out_size, void* d_ws, size_t ws_size,
                              hipStream_t stream) {
    const float* emb_i = (const float*)d_in[0];
    const float* emb_j = (const float*)d_in[1];

    __bf16*   zb       = (__bf16*)d_ws;                                 // 4 MB
    float*    g_denom  = (float*)((char*)d_ws + (size_t)N2 * D * 2);    // 8192 fp32
    float*    g_pos    = g_denom + N2;                                  // 8192 fp32
    unsigned* g_ticket = (unsigned*)(g_pos + N2);                       // 1 u32
    float*    out      = (float*)d_out;

    prep_kernel<<<NHALF / 4, 256, 0, stream>>>(emb_i, emb_j, zb, g_pos, g_denom, g_ticket);
    sim_kernel<<<NBLK2, 256, 0, stream>>>(zb, g_denom, g_pos, g_ticket, out);
}

// Round 11
// 137.644 us; speedup vs baseline: 1.7723x; 1.7723x over previous
//
#include <hip/hip_runtime.h>
#include <hip/hip_bf16.h>
#include <math.h>

#define D      256
#define N2     8192
#define NHALF  4096
#define TILE   128
#define BK     64
#define NCH    4        // 256 / BK
#define LDW    68       // LDS row stride in bf16 (136 B): bank start = 2*row+4*quad -> exact 2-way (free, r5-verified 0 conflicts)
#define NBLK2  4096     // sim grid: 64x64 tiles, one per block (r5-verified)

typedef __bf16 bf16x8_t __attribute__((ext_vector_type(8)));
typedef __bf16 bf16x4_t __attribute__((ext_vector_type(4)));
typedef float  f32x4_t  __attribute__((ext_vector_type(4)));

// ---------------- kernel 1: fused normalize + positives + denom/ticket zero --------
__global__ __launch_bounds__(256) void prep_kernel(const float* __restrict__ a,
                                                   const float* __restrict__ b,
                                                   __bf16* __restrict__ zb,
                                                   float* __restrict__ g_pos,
                                                   float* __restrict__ g_denom,
                                                   unsigned* __restrict__ g_ticket) {
    const int tid = threadIdx.x;
    const int gt  = blockIdx.x * 256 + tid;
    if (gt < N2) g_denom[gt] = 0.0f;
    if (gt == 0) *g_ticket = 0u;

    const int w = blockIdx.x * 4 + (tid >> 6);  // pair row in [0, NHALF)
    const int l = tid & 63;
    float4 x = ((const float4*)(a + (size_t)w * D))[l];
    float4 y = ((const float4*)(b + (size_t)w * D))[l];
    float sxx = x.x * x.x + x.y * x.y + x.z * x.z + x.w * x.w;
    float syy = y.x * y.x + y.y * y.y + y.z * y.z + y.w * y.w;
    float sxy = x.x * y.x + x.y * y.y + x.z * y.z + x.w * y.w;
    #pragma unroll
    for (int off = 32; off; off >>= 1) {
        sxx += __shfl_xor(sxx, off, 64);
        syy += __shfl_xor(syy, off, 64);
        sxy += __shfl_xor(sxy, off, 64);
    }
    const float rx = 1.0f / fmaxf(sqrtf(sxx), 1e-8f);
    const float ry = 1.0f / fmaxf(sqrtf(syy), 1e-8f);

    bf16x4_t ox, oy;
    ox[0] = (__bf16)(x.x * rx); ox[1] = (__bf16)(x.y * rx);
    ox[2] = (__bf16)(x.z * rx); ox[3] = (__bf16)(x.w * rx);
    oy[0] = (__bf16)(y.x * ry); oy[1] = (__bf16)(y.y * ry);
    oy[2] = (__bf16)(y.z * ry); oy[3] = (__bf16)(y.w * ry);
    *(bf16x4_t*)(zb + (size_t)w * D + l * 4)           = ox;
    *(bf16x4_t*)(zb + (size_t)(w + NHALF) * D + l * 4) = oy;

    if (l == 0) {
        const float p = sxy * rx * ry;
        g_pos[w]         = p;
        g_pos[w + NHALF] = p;
    }
}

// ---------------- kernel 2: round-5 sim (byte-exact) + FENCELESS ticket fin --------
// Round-10 post-mortem: identical static code to round 5 ran uniformly 2.9x slower
// (MfmaUtil/VALU/hbm all /2.9 at same VGPR/LDS/conflicts). Cause: the per-block
// __threadfence + ACQ_REL agent RMW compile to L2-invalidating cache-maintenance
// (per-XCD L2s are non-coherent, so agent acquire invalidates the XCD L2) -- 4096
// blocks nuked each XCD's L2 ~1000x, evicting the L2-resident zb panels under every
// running block. Fix: RELAXED ticket, no threadfence. Correctness: g_denom is only
// ever written by device-scope atomicAdd (coherent at device coherence point, G12)
// and read by agent-scope atomic loads; "my adds complete before my ticket bump"
// needs only vmcnt(0), which __syncthreads already provides (compiler drains vmcnt
// before s_barrier -- m97 asm) + explicit belt-and-suspenders waitcnt in lane 0.
// No cache-maintenance instructions remain anywhere in the kernel.
__global__ __launch_bounds__(256, 2) void sim_kernel(const __bf16* __restrict__ zb,
                                                     float* __restrict__ g_denom,
                                                     const float* __restrict__ g_pos,
                                                     unsigned* __restrict__ g_ticket,
                                                     float* __restrict__ out) {
    __shared__ __bf16 ldsA[2][TILE * LDW];
    __shared__ __bf16 ldsB[2][TILE * LDW];
    __shared__ float  sw[4];
    __shared__ bool   amLast;

    const int tid    = threadIdx.x;
    const int l      = tid & 63;
    const int lane15 = l & 15;
    const int quad   = l >> 4;
    const int w      = tid >> 6;
    const int wr     = (w >> 1) * 64;          // wave row offset in tile
    const int wc     = (w & 1) * 64;           // wave col offset in tile

    const int bi = blockIdx.x >> 6;            // row block [0,64)
    const int bj = blockIdx.x & 63;            // col block [0,64)

    // staging map: thread t -> row r = t>>1, half = t&1 (64 B each), 4 x b128 units
    const int r    = tid >> 1;
    const int half = tid & 1;
    const __bf16* ga = zb + (size_t)(bi * TILE + r) * D + half * 32;
    const __bf16* gb = zb + (size_t)(bj * TILE + r) * D + half * 32;
    const int wofs = r * LDW + half * 32;

    bf16x8_t sa[4], sb[4];
    auto load_regs = [&](int c) {
        const int k0 = c * BK;
        #pragma unroll
        for (int u = 0; u < 4; ++u) {
            sa[u] = *(const bf16x8_t*)(ga + k0 + u * 8);
            sb[u] = *(const bf16x8_t*)(gb + k0 + u * 8);
        }
    };
    auto write_lds = [&](int buf) {
        #pragma unroll
        for (int u = 0; u < 4; ++u) {
            *(bf16x8_t*)(&ldsA[buf][wofs + u * 8]) = sa[u];
            *(bf16x8_t*)(&ldsB[buf][wofs + u * 8]) = sb[u];
        }
    };

    f32x4_t acc[4][4];
    #pragma unroll
    for (int mi = 0; mi < 4; ++mi)
        #pragma unroll
        for (int nj = 0; nj < 4; ++nj)
            acc[mi][nj] = (f32x4_t){0.f, 0.f, 0.f, 0.f};

    auto compute = [&](int buf) {
        #pragma unroll
        for (int ks = 0; ks < 2; ++ks) {
            bf16x8_t af[4], bff[4];
            #pragma unroll
            for (int mi = 0; mi < 4; ++mi)
                af[mi] = *(const bf16x8_t*)(&ldsA[buf][(wr + mi * 16 + lane15) * LDW + ks * 32 + quad * 8]);
            #pragma unroll
            for (int nj = 0; nj < 4; ++nj)
                bff[nj] = *(const bf16x8_t*)(&ldsB[buf][(wc + nj * 16 + lane15) * LDW + ks * 32 + quad * 8]);
            #pragma unroll
            for (int mi = 0; mi < 4; ++mi)
                #pragma unroll
                for (int nj = 0; nj < 4; ++nj)
                    acc[mi][nj] = __builtin_amdgcn_mfma_f32_16x16x32_bf16(bff[nj], af[mi], acc[mi][nj], 0, 0, 0);
        }
    };

    // prologue: stage chunk 0
    load_regs(0);
    write_lds(0);
    __syncthreads();

    int cur = 0;
    #pragma unroll
    for (int c = 0; c < NCH; ++c) {
        if (c + 1 < NCH) load_regs(c + 1);
        compute(cur);
        if (c + 1 < NCH) {
            write_lds(cur ^ 1);     // safe: buf[cur^1] readers all passed prior barrier
            __syncthreads();
            cur ^= 1;
        }
    }

    // epilogue: e = exp(sim/T) = exp2(acc * 2/ln2); zero self-similarity; row sums
    // acc[mi][nj]: S-row = bi*128+wr+mi*16+lane15, S-col = bj*128+wc+nj*16+quad*4+t
    const bool dw = (bi == bj) && (wr == wc);
    float rs[4] = {0.f, 0.f, 0.f, 0.f};
    #pragma unroll
    for (int mi = 0; mi < 4; ++mi) {
        #pragma unroll
        for (int nj = 0; nj < 4; ++nj) {
            #pragma unroll
            for (int t = 0; t < 4; ++t) {
                float e = exp2f(acc[mi][nj][t] * 2.8853900817779268f);
                if (dw && mi == nj && (quad * 4 + t) == lane15) e = 0.0f;
                rs[mi] += e;
            }
        }
    }
    // reduce the 4 quads holding the same row, then one atomic per row
    #pragma unroll
    for (int mi = 0; mi < 4; ++mi) {
        rs[mi] += __shfl_xor(rs[mi], 16, 64);
        rs[mi] += __shfl_xor(rs[mi], 32, 64);
    }
    if (l < 16) {
        #pragma unroll
        for (int mi = 0; mi < 4; ++mi)
            atomicAdd(&g_denom[bi * TILE + wr + mi * 16 + l], rs[mi]);
    }

    // ---------------- fenceless last-block fin ----------------
    __syncthreads();                 // drains vmcnt for every wave -> adds complete
    if (tid == 0) {
        asm volatile("s_waitcnt vmcnt(0)" ::: "memory");   // belt-and-suspenders
        unsigned t = __hip_atomic_fetch_add(g_ticket, 1u, __ATOMIC_RELAXED,
                                            __HIP_MEMORY_SCOPE_AGENT);
        amLast = (t == NBLK2 - 1);
    }
    __syncthreads();
    if (!amLast) return;

    float local = 0.0f;
    for (int k = tid; k < N2; k += 256) {
        float dn = __hip_atomic_load(&g_denom[k], __ATOMIC_RELAXED,
                                     __HIP_MEMORY_SCOPE_AGENT);
        local += logf(dn) - 2.0f * g_pos[k];
    }
    #pragma unroll
    for (int off = 32; off; off >>= 1) local += __shfl_xor(local, off, 64);
    if (l == 0) sw[tid >> 6] = local;
    __syncthreads();
    if (tid == 0) out[0] = (sw[0] + sw[1] + sw[2] + sw[3]) / (float)N2;
}

extern "C" void kernel_launch(void* const* d_in, const int* in_sizes, int n_in,
                              void* d_out, int out_size, void* d_ws, size_t ws_size,
                              hipStream_t stream) {
    const float* emb_i = (const float*)d_in[0];
    const float* emb_j = (const float*)d_in[1];

    __bf16*   zb       = (__bf16*)d_ws;                                 // 4 MB
    float*    g_denom  = (float*)((char*)d_ws + (size_t)N2 * D * 2);    // 8192 fp32
    float*    g_pos    = g_denom + N2;                                  // 8192 fp32
    unsigned* g_ticket = (unsigned*)(g_pos + N2);                       // 1 u32
    float*    out      = (float*)d_out;

    prep_kernel<<<NHALF / 4, 256, 0, stream>>>(emb_i, emb_j, zb, g_pos, g_denom, g_ticket);
    sim_kernel<<<NBLK2, 256, 0, stream>>>(zb, g_denom, g_pos, g_ticket, out);
}

// Round 12
// 122.393 us; speedup vs baseline: 1.9932x; 1.1246x over previous
//
#include <hip/hip_runtime.h>
#include <hip/hip_bf16.h>
#include <math.h>

#define D      256
#define N2     8192
#define NHALF  4096
#define TILE   128
#define BK     64
#define NCH    4        // 256 / BK
#define LDW    68       // 136B row stride: bank start = 2*row+4*quad+16*ks -> exact 2-way (r5-verified 0 conflicts)
#define NBLK2  4096     // 64x64 tiles, one per block
#define TPB    512      // 8 waves/block, 2 blocks/CU -> 4 waves/SIMD (vs r5's 2)

typedef __bf16 bf16x8_t __attribute__((ext_vector_type(8)));
typedef __bf16 bf16x4_t __attribute__((ext_vector_type(4)));
typedef float  f32x4_t  __attribute__((ext_vector_type(4)));

// ---------------- kernel 1: fused normalize + positives + denom/ticket zero --------
__global__ __launch_bounds__(256) void prep_kernel(const float* __restrict__ a,
                                                   const float* __restrict__ b,
                                                   __bf16* __restrict__ zb,
                                                   float* __restrict__ g_pos,
                                                   float* __restrict__ g_denom,
                                                   unsigned* __restrict__ g_t1) {
    const int tid = threadIdx.x;
    const int gt  = blockIdx.x * 256 + tid;
    if (gt < N2) g_denom[gt] = 0.0f;
    if (gt < 64 * 32 + 1) g_t1[gt] = 0u;       // 64 spaced L1 tickets + 1 L2 ticket

    const int w = blockIdx.x * 4 + (tid >> 6);  // pair row in [0, NHALF)
    const int l = tid & 63;
    float4 x = ((const float4*)(a + (size_t)w * D))[l];
    float4 y = ((const float4*)(b + (size_t)w * D))[l];
    float sxx = x.x * x.x + x.y * x.y + x.z * x.z + x.w * x.w;
    float syy = y.x * y.y * 0.0f + y.x * y.x + y.y * y.y + y.z * y.z + y.w * y.w;
    float sxy = x.x * y.x + x.y * y.y + x.z * y.z + x.w * y.w;
    #pragma unroll
    for (int off = 32; off; off >>= 1) {
        sxx += __shfl_xor(sxx, off, 64);
        syy += __shfl_xor(syy, off, 64);
        sxy += __shfl_xor(sxy, off, 64);
    }
    const float rx = 1.0f / fmaxf(sqrtf(sxx), 1e-8f);
    const float ry = 1.0f / fmaxf(sqrtf(syy), 1e-8f);

    bf16x4_t ox, oy;
    ox[0] = (__bf16)(x.x * rx); ox[1] = (__bf16)(x.y * rx);
    ox[2] = (__bf16)(x.z * rx); ox[3] = (__bf16)(x.w * rx);
    oy[0] = (__bf16)(y.x * ry); oy[1] = (__bf16)(y.y * ry);
    oy[2] = (__bf16)(y.z * ry); oy[3] = (__bf16)(y.w * ry);
    *(bf16x4_t*)(zb + (size_t)w * D + l * 4)           = ox;
    *(bf16x4_t*)(zb + (size_t)(w + NHALF) * D + l * 4) = oy;

    if (l == 0) {
        const float p = sxy * rx * ry;
        g_pos[w]         = p;
        g_pos[w + NHALF] = p;
    }
}

// ---------------- kernel 2: 512-thread r5-layout sim + two-level fenceless fin ----
// r11 post-mortem: fence removal fixed the 2.9x L2-invalidation catastrophe (194->83)
// but sim still carries ~17us of tail vs r5's 66: 4096 relaxed RMWs on ONE cache
// line serialize at the coherence point while each retiring block holds its CU slot.
// Fix 1: two-level tickets -- 64 per-bi counters on separate lines (64 RMWs each),
// group-last bumps the single global line (64 RMWs total). Fix 2 (sim core): r5 runs
// 8 barrier-locked waves/CU (2/SIMD); chunk period 4950cyc vs ~1600cyc work. Same
// 128^2 tile and BYTE-IDENTICAL LDS bank layout (LDW=68, verified 0 conflicts), but
// 512-thread blocks: 8 waves x 2 independent blocks/CU = 4 waves/SIMD. Wave tile
// 32x64 -> acc 32 VGPR, demand ~90 well under the 128 cap of (512,4) -- no r7 spill.
__global__ __launch_bounds__(TPB, 4) void sim_kernel(const __bf16* __restrict__ zb,
                                                     float* __restrict__ g_denom,
                                                     const float* __restrict__ g_pos,
                                                     unsigned* __restrict__ g_t1,
                                                     float* __restrict__ out) {
    __shared__ __bf16 ldsA[2][TILE * LDW];
    __shared__ __bf16 ldsB[2][TILE * LDW];
    __shared__ float  sw[8];
    __shared__ bool   amLast;

    const int tid    = threadIdx.x;
    const int l      = tid & 63;
    const int lane15 = l & 15;
    const int quad   = l >> 4;
    const int w      = tid >> 6;               // wave 0..7
    const int wr     = (w & 3) * 32;           // wave rows: 32
    const int wc     = (w >> 2) * 64;          // wave cols: 64

    const int bi = blockIdx.x >> 6;            // row block [0,64)
    const int bj = blockIdx.x & 63;            // col block [0,64)

    // staging map: thread t -> row r = t>>2 (0..127), units u and u+4 (u = t&3)
    const int r = tid >> 2;
    const int u = tid & 3;
    const __bf16* ga = zb + (size_t)(bi * TILE + r) * D + u * 8;
    const __bf16* gb = zb + (size_t)(bj * TILE + r) * D + u * 8;
    const int wofs = r * LDW + u * 8;

    bf16x8_t sa0, sa1, sb0, sb1;
    auto load_regs = [&](int c) {
        const int k0 = c * BK;
        sa0 = *(const bf16x8_t*)(ga + k0);
        sa1 = *(const bf16x8_t*)(ga + k0 + 32);
        sb0 = *(const bf16x8_t*)(gb + k0);
        sb1 = *(const bf16x8_t*)(gb + k0 + 32);
    };
    auto write_lds = [&](int buf) {
        *(bf16x8_t*)(&ldsA[buf][wofs])      = sa0;
        *(bf16x8_t*)(&ldsA[buf][wofs + 32]) = sa1;
        *(bf16x8_t*)(&ldsB[buf][wofs])      = sb0;
        *(bf16x8_t*)(&ldsB[buf][wofs + 32]) = sb1;
    };

    f32x4_t acc[2][4];
    #pragma unroll
    for (int mi = 0; mi < 2; ++mi)
        #pragma unroll
        for (int nj = 0; nj < 4; ++nj)
            acc[mi][nj] = (f32x4_t){0.f, 0.f, 0.f, 0.f};

    auto compute = [&](int buf) {
        #pragma unroll
        for (int ks = 0; ks < 2; ++ks) {
            bf16x8_t af[2], bff[4];
            #pragma unroll
            for (int mi = 0; mi < 2; ++mi)
                af[mi] = *(const bf16x8_t*)(&ldsA[buf][(wr + mi * 16 + lane15) * LDW + ks * 32 + quad * 8]);
            #pragma unroll
            for (int nj = 0; nj < 4; ++nj)
                bff[nj] = *(const bf16x8_t*)(&ldsB[buf][(wc + nj * 16 + lane15) * LDW + ks * 32 + quad * 8]);
            #pragma unroll
            for (int mi = 0; mi < 2; ++mi)
                #pragma unroll
                for (int nj = 0; nj < 4; ++nj)
                    acc[mi][nj] = __builtin_amdgcn_mfma_f32_16x16x32_bf16(bff[nj], af[mi], acc[mi][nj], 0, 0, 0);
        }
    };

    // prologue: stage chunk 0
    load_regs(0);
    write_lds(0);
    __syncthreads();

    int cur = 0;
    #pragma unroll
    for (int c = 0; c < NCH; ++c) {
        if (c + 1 < NCH) load_regs(c + 1);
        compute(cur);
        if (c + 1 < NCH) {
            write_lds(cur ^ 1);     // safe: buf[cur^1] readers all passed prior barrier
            __syncthreads();
            cur ^= 1;
        }
    }

    // epilogue: e = exp(sim/T) = exp2(acc * 2/ln2); zero self-similarity; row sums
    // acc[mi][nj]: S-row = bi*128+wr+mi*16+lane15, S-col = bj*128+wc+nj*16+quad*4+t
    float rs[2] = {0.f, 0.f};
    #pragma unroll
    for (int mi = 0; mi < 2; ++mi) {
        #pragma unroll
        for (int nj = 0; nj < 4; ++nj) {
            const bool dn = (bi == bj) && (wr + mi * 16 == wc + nj * 16);  // diag frag (wave-uniform)
            #pragma unroll
            for (int t = 0; t < 4; ++t) {
                float e = exp2f(acc[mi][nj][t] * 2.8853900817779268f);
                if (dn && (quad * 4 + t) == lane15) e = 0.0f;
                rs[mi] += e;
            }
        }
    }
    #pragma unroll
    for (int mi = 0; mi < 2; ++mi) {
        rs[mi] += __shfl_xor(rs[mi], 16, 64);
        rs[mi] += __shfl_xor(rs[mi], 32, 64);
    }
    if (l < 16) {
        #pragma unroll
        for (int mi = 0; mi < 2; ++mi)
            atomicAdd(&g_denom[bi * TILE + wr + mi * 16 + l], rs[mi]);
    }

    // ---------------- two-level fenceless ticket fin ----------------
    __syncthreads();                 // drains vmcnt for every wave -> adds complete
    if (tid == 0) {
        asm volatile("s_waitcnt vmcnt(0)" ::: "memory");
        unsigned t1 = __hip_atomic_fetch_add(&g_t1[bi * 32], 1u, __ATOMIC_RELAXED,
                                             __HIP_MEMORY_SCOPE_AGENT);
        bool grpLast = (t1 == 63);
        unsigned t2 = 0;
        if (grpLast)
            t2 = __hip_atomic_fetch_add(&g_t1[64 * 32], 1u, __ATOMIC_RELAXED,
                                        __HIP_MEMORY_SCOPE_AGENT);
        amLast = grpLast && (t2 == 63);
    }
    __syncthreads();
    if (!amLast) return;

    float local = 0.0f;
    for (int k = tid; k < N2; k += TPB) {
        float dn = __hip_atomic_load(&g_denom[k], __ATOMIC_RELAXED,
                                     __HIP_MEMORY_SCOPE_AGENT);
        local += logf(dn) - 2.0f * g_pos[k];
    }
    #pragma unroll
    for (int off = 32; off; off >>= 1) local += __shfl_xor(local, off, 64);
    if (l == 0) sw[w] = local;
    __syncthreads();
    if (tid == 0) {
        float s = 0.f;
        #pragma unroll
        for (int i = 0; i < 8; ++i) s += sw[i];
        out[0] = s / (float)N2;
    }
}

extern "C" void kernel_launch(void* const* d_in, const int* in_sizes, int n_in,
                              void* d_out, int out_size, void* d_ws, size_t ws_size,
                              hipStream_t stream) {
    const float* emb_i = (const float*)d_in[0];
    const float* emb_j = (const float*)d_in[1];

    __bf16*   zb      = (__bf16*)d_ws;                                 // 4 MB
    float*    g_denom = (float*)((char*)d_ws + (size_t)N2 * D * 2);    // 8192 fp32
    float*    g_pos   = g_denom + N2;                                  // 8192 fp32
    unsigned* g_t1    = (unsigned*)(g_pos + N2);                       // 64*32+1 u32 tickets
    float*    out     = (float*)d_out;

    prep_kernel<<<NHALF / 4, 256, 0, stream>>>(emb_i, emb_j, zb, g_pos, g_denom, g_t1);
    sim_kernel<<<NBLK2, TPB, 0, stream>>>(zb, g_denom, g_pos, g_t1, out);
}